// Round 12
// baseline (133.072 us; speedup 1.0000x reference)
//
#include <hip/hip_runtime.h>
#include <hip/hip_bf16.h>

#define N_NODES 100000
#define IN_DIM 128
#define HID_DIM 128
#define N_EDGES 1600000
#define NBK 196         // node buckets: 512 nodes each (196*512 = 100352)
#define BCAP 10240      // bucket capacity: E[sz]=8192, sigma~90, +22 sigma
#define BK_EDGES 4096   // edges staged per binA block
#define NBIN 391        // ceil(N_EDGES / BK_EDGES)
#define NGEMM 1563      // ceil(N_NODES / 64)
#define G1 625          // gemm blocks co-launched with binA
#define G2 (NGEMM - G1) // gemm blocks co-launched with buildB
#define LDK 136         // padded fp16 row length in LDS
#define SMEM_BYTES 22848

using half8 = __attribute__((ext_vector_type(8))) _Float16;
using half4 = __attribute__((ext_vector_type(4))) _Float16;
using f32x4 = __attribute__((ext_vector_type(4))) float;

// ---------------- prep: gcur zero + W -> Wt fp16 transposed [col][k] -------
__global__ void k_prep(int* __restrict__ gcur, const float* __restrict__ w,
                       _Float16* __restrict__ wt) {
    int i = blockIdx.x * 256 + threadIdx.x;
    if (i < NBK) gcur[i] = 0;
    if (i < IN_DIM * HID_DIM) {
        int k = i >> 7, c = i & 127;
        wt[c * 128 + k] = (_Float16)w[i];
    }
}

// ------ gemm role: h[brow..brow+64) = x @ W.  A staged in LDS; B read
// directly from global wt (32 KB, L2-resident across all 1563 blocks) -------
__device__ __forceinline__ void gemm_role(char* smem, int tid, int brow,
                                          const float* __restrict__ x,
                                          const _Float16* __restrict__ wt,
                                          _Float16* __restrict__ h) {
    _Float16* xs = (_Float16*)smem;            // 64*LDK*2 = 17408 B
    {   // stage x: 4 threads/row, 32 f32 each -> fp16
        int row = tid >> 2;
        int seg = (tid & 3) * 32;
        int grow = brow + row; if (grow > N_NODES - 1) grow = N_NODES - 1;
        const float4* p = reinterpret_cast<const float4*>(&x[(size_t)grow * IN_DIM + seg]);
#pragma unroll
        for (int i = 0; i < 8; ++i) {
            float4 v = p[i];
            half4 hv = {(_Float16)v.x, (_Float16)v.y, (_Float16)v.z, (_Float16)v.w};
            *reinterpret_cast<half4*>(&xs[row * LDK + seg + i * 4]) = hv;
        }
    }
    __syncthreads();

    const int lane = tid & 63;
    const int m0   = (tid >> 6) * 16;
    const int arow = m0 + (lane & 15);
    const int kgrp = (lane >> 4) * 8;
    const int bcol = lane & 15;
    f32x4 acc[8] = {};
#pragma unroll
    for (int k0 = 0; k0 < 128; k0 += 32) {
        half8 a = *reinterpret_cast<const half8*>(&xs[arow * LDK + k0 + kgrp]);
#pragma unroll
        for (int nb = 0; nb < 8; ++nb) {
            half8 b = *reinterpret_cast<const half8*>(
                &wt[(nb * 16 + bcol) * 128 + k0 + kgrp]);   // L2-hot global
            acc[nb] = __builtin_amdgcn_mfma_f32_16x16x32_f16(a, b, acc[nb], 0, 0, 0);
        }
    }
#pragma unroll
    for (int nb = 0; nb < 8; ++nb) {
#pragma unroll
        for (int r = 0; r < 4; ++r) {
            int node = brow + m0 + (lane >> 4) * 4 + r;
            int feat = nb * 16 + bcol;
            if (node < N_NODES) h[(size_t)node * HID_DIM + feat] = (_Float16)acc[nb][r];
        }
    }
}

// ------------- k1: blocks [0,NBIN) = binA ; [NBIN,NBIN+G1) = gemm ----------
// bucket entry packed u32: (src << 9) | (dst & 511); bucket id in u8 side arr.
__global__ __launch_bounds__(256) void k_fat1(const int* __restrict__ ei,
                                              const float* __restrict__ x,
                                              const _Float16* __restrict__ wt,
                                              _Float16* __restrict__ h,
                                              int* __restrict__ gcur,
                                              unsigned* __restrict__ bucket) {
    __shared__ __align__(16) char smem[SMEM_BYTES];
    const int tid = threadIdx.x;

    if (blockIdx.x >= NBIN) {
        gemm_role(smem, tid, (blockIdx.x - NBIN) * 64, x, wt, h);
        return;
    }
    // ---------------- binA role: edges -> dst-window buckets --------------
    unsigned* stage = (unsigned*)smem;                    // 16384 B
    unsigned char* bkid = (unsigned char*)(smem + 16384); // 4096 B
    int* hist  = (int*)(smem + 20480);                    // 784 B
    int* lbase = (int*)(smem + 21264);                    // 784 B
    int* lcur  = (int*)(smem + 22048);                    // 784 B
    int* s64   = (int*)(smem + 22832);                    // 16 B
    for (int b = tid; b < NBK; b += 256) { hist[b] = 0; lcur[b] = 0; }
    if (tid < 64) {                            // int64 layout probe
        int v = ei[2 * tid + 1];
        int all0 = __all(v == 0);
        if (tid == 0) *s64 = all0;
    }
    __syncthreads();
    const int is64 = *s64;
    const int e0 = blockIdx.x * BK_EDGES;
    const int valid = min(BK_EDGES, N_EDGES - e0);

#pragma unroll
    for (int k = 0; k < 8; ++k) {
        int el = k * 512 + 2 * tid;
        if (el >= valid) break;
        int e = e0 + el;
        int s0, s1, d0, d1;
        if (is64) {
            int4 vs = reinterpret_cast<const int4*>(ei)[e >> 1];
            int4 vd = (reinterpret_cast<const int4*>(ei) + N_EDGES / 2)[e >> 1];
            s0 = vs.x; s1 = vs.z; d0 = vd.x; d1 = vd.z;
        } else {
            int2 vs = reinterpret_cast<const int2*>(ei)[e >> 1];
            int2 vd = reinterpret_cast<const int2*>(ei + N_EDGES)[e >> 1];
            s0 = vs.x; s1 = vs.y; d0 = vd.x; d1 = vd.y;
        }
        stage[el]     = ((unsigned)s0 << 9) | ((unsigned)d0 & 511u);
        stage[el + 1] = ((unsigned)s1 << 9) | ((unsigned)d1 & 511u);
        bkid[el]      = (unsigned char)(d0 >> 9);
        bkid[el + 1]  = (unsigned char)(d1 >> 9);
        atomicAdd(&hist[d0 >> 9], 1);
        atomicAdd(&hist[d1 >> 9], 1);
    }
    __syncthreads();
    for (int b = tid; b < NBK; b += 256)
        if (hist[b] > 0) lbase[b] = atomicAdd(&gcur[b], hist[b]);
    __syncthreads();
    for (int i = tid; i < valid; i += 256) {
        unsigned v = stage[i];
        int b = bkid[i];
        int pos = lbase[b] + atomicAdd(&lcur[b], 1);
        if (pos < BCAP) bucket[(size_t)b * BCAP + pos] = v;
    }
}

// ------------- k2: blocks [0,NBK) = buildB ; [NBK,NBK+G2) = gemm -----------
__global__ __launch_bounds__(256) void k_fat2(const int* __restrict__ gcur,
                                              const unsigned* __restrict__ bucket,
                                              float* __restrict__ dinv,
                                              int2* __restrict__ rc,
                                              int* __restrict__ csr_src,
                                              const float* __restrict__ x,
                                              const _Float16* __restrict__ wt,
                                              _Float16* __restrict__ h) {
    __shared__ __align__(16) char smem[SMEM_BYTES];
    const int tid = threadIdx.x;

    if (blockIdx.x >= NBK) {
        gemm_role(smem, tid, (G1 + blockIdx.x - NBK) * 64, x, wt, h);
        return;
    }
    // ---------------- buildB role (single-pass, entries in registers) -----
    int* sizes = (int*)smem;                   // 784 B
    int* ncnt  = (int*)(smem + 784);           // 2048
    int* nloff = (int*)(smem + 2832);          // 2048
    int* ncur  = (int*)(smem + 4880);          // 2048
    int* wtot  = (int*)(smem + 6928);          // 16
    int* base_p = (int*)(smem + 6944);
    const int b = blockIdx.x;
    for (int i = tid; i < NBK; i += 256) sizes[i] = gcur[i];
    ncnt[tid] = 0; ncnt[tid + 256] = 0; ncur[tid] = 0; ncur[tid + 256] = 0;
    __syncthreads();
    const int sz = min(sizes[b], BCAP);
    if (tid < 64) {                 // wave-parallel: base = sum sizes[0..b)
        int part = 0;
        for (int i = tid; i < b; i += 64) part += sizes[i];
#pragma unroll
        for (int d = 32; d; d >>= 1) part += __shfl_xor(part, d);
        if (tid == 0) *base_p = part;
    }
    const int n0 = b * 512;
    const unsigned* bk = bucket + (size_t)b * BCAP;
    unsigned ent[40];               // BCAP/256 = 40, fully unrolled (static idx)
#pragma unroll
    for (int j = 0; j < 40; ++j) {
        int i = j * 256 + tid;
        unsigned v = 0xFFFFFFFFu;
        if (i < sz) { v = bk[i]; atomicAdd(&ncnt[v & 511u], 1); }
        ent[j] = v;
    }
    __syncthreads();
    // 2-level exclusive scan over ncnt[512]
    int c0 = ncnt[2 * tid], c1 = ncnt[2 * tid + 1];
    int pair = c0 + c1;
    int lane = tid & 63, wv = tid >> 6;
    int scan = pair;
#pragma unroll
    for (int d = 1; d < 64; d <<= 1) {
        int t = __shfl_up(scan, d);
        if (lane >= d) scan += t;
    }
    if (lane == 63) wtot[wv] = scan;
    int excl = scan - pair;
    __syncthreads();
#pragma unroll
    for (int i = 0; i < 4; ++i) if (i < wv) excl += wtot[i];
    nloff[2 * tid] = excl;
    nloff[2 * tid + 1] = excl + c0;
    __syncthreads();
    const int base = *base_p;
    for (int i = tid; i < 512; i += 256) {
        int node = n0 + i;
        if (node < N_NODES) {
            int c = ncnt[i];
            dinv[node] = rsqrtf((float)(c + 1));
            rc[node] = make_int2(base + nloff[i], c);
        }
    }
#pragma unroll
    for (int j = 0; j < 40; ++j) {
        unsigned v = ent[j];
        if (v != 0xFFFFFFFFu) {
            int li = v & 511u;
            int pos = atomicAdd(&ncur[li], 1);
            csr_src[base + nloff[li] + pos] = (int)(v >> 9);
        }
    }
}

// ------- gather (round-8 proven): 16 lanes/node, chunk-32, early-exit ------
#define GSTEP(J, SE, DS) {                                                   \
    int s_ = __shfl(SE, hi | (J));                                           \
    float w_ = __shfl(DS, hi | (J));                                         \
    half8 v_ = *reinterpret_cast<const half8*>(hbase + (size_t)s_ * HID_DIM);\
    acc[0] = fmaf((float)v_[0], w_, acc[0]);                                 \
    acc[1] = fmaf((float)v_[1], w_, acc[1]);                                 \
    acc[2] = fmaf((float)v_[2], w_, acc[2]);                                 \
    acc[3] = fmaf((float)v_[3], w_, acc[3]);                                 \
    acc[4] = fmaf((float)v_[4], w_, acc[4]);                                 \
    acc[5] = fmaf((float)v_[5], w_, acc[5]);                                 \
    acc[6] = fmaf((float)v_[6], w_, acc[6]);                                 \
    acc[7] = fmaf((float)v_[7], w_, acc[7]); }
#define GGRP(B, SE, DS) \
    GSTEP(B + 0, SE, DS) GSTEP(B + 1, SE, DS) GSTEP(B + 2, SE, DS) \
    GSTEP(B + 3, SE, DS) GSTEP(B + 4, SE, DS) GSTEP(B + 5, SE, DS) \
    GSTEP(B + 6, SE, DS) GSTEP(B + 7, SE, DS)

__global__ __launch_bounds__(256) void k_gather(const _Float16* __restrict__ h,
                                                const int* __restrict__ csr_src,
                                                const int2* __restrict__ rc,
                                                const float* __restrict__ dinv,
                                                const float* __restrict__ bias,
                                                float* __restrict__ out) {
    const int lane = threadIdx.x & 63;
    const int l4   = lane & 15;
    const int hi   = lane & 48;
    const int node = blockIdx.x * 16 + (threadIdx.x >> 6) * 4 + (lane >> 4);
    const int2 rcv = rc[node];
    const int rs = rcv.x;
    const int n  = rcv.y;
    const float di = dinv[node];
    const int tq = n + 1;                 // slots incl self loop
    const _Float16* hbase = h + l4 * 8;

    float acc[8] = {};

    for (int c0 = 0; c0 < tq; c0 += 32) {
        int t0 = c0 + l4, t1 = t0 + 16;
        int se0 = node, se1 = node;
        float dw0 = 0.0f, dw1 = 0.0f;
        if (t0 < n)       { se0 = csr_src[rs + t0]; dw0 = dinv[se0]; }
        else if (t0 == n)   dw0 = di;
        if (t1 < n)       { se1 = csr_src[rs + t1]; dw1 = dinv[se1]; }
        else if (t1 == n)   dw1 = di;

        GGRP(0, se0, dw0)
        if (tq <= c0 + 8) continue;
        GGRP(8, se0, dw0)
        if (tq <= c0 + 16) continue;
        GGRP(0, se1, dw1)
        if (tq <= c0 + 24) continue;
        GGRP(8, se1, dw1)
    }

    float4 bv0 = *reinterpret_cast<const float4*>(&bias[l4 * 8]);
    float4 bv1 = *reinterpret_cast<const float4*>(&bias[l4 * 8 + 4]);
    float4 o0, o1;
    o0.x = fmaxf(fmaf(di, acc[0], bv0.x), 0.0f);
    o0.y = fmaxf(fmaf(di, acc[1], bv0.y), 0.0f);
    o0.z = fmaxf(fmaf(di, acc[2], bv0.z), 0.0f);
    o0.w = fmaxf(fmaf(di, acc[3], bv0.w), 0.0f);
    o1.x = fmaxf(fmaf(di, acc[4], bv1.x), 0.0f);
    o1.y = fmaxf(fmaf(di, acc[5], bv1.y), 0.0f);
    o1.z = fmaxf(fmaf(di, acc[6], bv1.z), 0.0f);
    o1.w = fmaxf(fmaf(di, acc[7], bv1.w), 0.0f);
    float* op = &out[(size_t)node * HID_DIM + l4 * 8];
    *reinterpret_cast<float4*>(op)     = o0;
    *reinterpret_cast<float4*>(op + 4) = o1;
}

// ---------------- launcher --------------------------------------------------
extern "C" void kernel_launch(void* const* d_in, const int* in_sizes, int n_in,
                              void* d_out, int out_size, void* d_ws, size_t ws_size,
                              hipStream_t stream) {
    const float* x    = (const float*)d_in[0];
    const int*   ei   = (const int*)d_in[1];
    const float* w    = (const float*)d_in[2];
    const float* bias = (const float*)d_in[3];
    float* out = (float*)d_out;

    // workspace layout (bytes), 16B-aligned; ~41.3 MB total
    char* wsb = (char*)d_ws;
    _Float16* h      = (_Float16*)(wsb);                  // 25,600,000
    float* dinv      = (float*)(wsb + 25600000);          // 400,000
    int2*  rc        = (int2*)(wsb + 26000000);           // 800,000
    int*   csr_src   = (int*)(wsb + 26800000);            // 6,400,000
    unsigned* bucket = (unsigned*)(wsb + 33200000);       // 196*10240*4 = 8,028,160
    _Float16* wt     = (_Float16*)(wsb + 41228160);       // 32,768
    int*   gcur      = (int*)(wsb + 41260928);            // 800

    k_prep  <<<64, 256, 0, stream>>>(gcur, w, wt);
    k_fat1  <<<NBIN + G1, 256, 0, stream>>>(ei, x, wt, h, gcur, bucket);
    k_fat2  <<<NBK + G2, 256, 0, stream>>>(gcur, bucket, dinv, rc, csr_src, x, wt, h);
    k_gather<<<N_NODES / 16, 256, 0, stream>>>(h, csr_src, rc, dinv, bias, out);
}

// Round 13
// 119.421 us; speedup vs baseline: 1.1143x; 1.1143x over previous
//
#include <hip/hip_runtime.h>
#include <hip/hip_bf16.h>

#define N_NODES 100000
#define IN_DIM 128
#define HID_DIM 128
#define N_EDGES 1600000
#define NBK 196         // node buckets: 512 nodes each (196*512 = 100352)
#define BCAP 10240      // bucket capacity: E[sz]=8192, sigma~90, +22 sigma
#define BK_EDGES 4096   // edges staged per binA block
#define NBIN 391        // ceil(N_EDGES / BK_EDGES)
#define NGEMM 1563      // ceil(N_NODES / 64)
#define G1 625          // gemm blocks co-launched with binA
#define G2 (NGEMM - G1) // gemm blocks co-launched with buildB
#define LDK 136         // padded fp16 row length in LDS (A tile)
#define LDKB 72         // padded fp16 half-row length (B tile half)
#define SMEM_BYTES 35840   // xs 17408 + ws-half 18432; 160K/35.8K -> 4 blk/CU

using half8 = __attribute__((ext_vector_type(8))) _Float16;
using half4 = __attribute__((ext_vector_type(4))) _Float16;
using f32x4 = __attribute__((ext_vector_type(4))) float;

// ---------------- prep: gcur zero + W -> Wt fp16 transposed [col][k] -------
__global__ void k_prep(int* __restrict__ gcur, const float* __restrict__ w,
                       _Float16* __restrict__ wt) {
    int i = blockIdx.x * 256 + threadIdx.x;
    if (i < NBK) gcur[i] = 0;
    if (i < IN_DIM * HID_DIM) {
        int k = i >> 7, c = i & 127;
        wt[c * 128 + k] = (_Float16)w[i];
    }
}

// ------ gemm role: h[brow..brow+64) = x @ W. A in LDS (full); B in LDS,
// staged in two K-halves to cut union LDS 52->35.8 KB (3->4 blocks/CU) ------
__device__ __forceinline__ void gemm_role(char* smem, int tid, int brow,
                                          const float* __restrict__ x,
                                          const _Float16* __restrict__ wt,
                                          _Float16* __restrict__ h) {
    _Float16* xs = (_Float16*)smem;            // 64*LDK*2  = 17408 B
    _Float16* ws = (_Float16*)(smem + 17408);  // 128*LDKB*2 = 18432 B
    {   // stage x: 4 threads/row, 32 f32 each -> fp16
        int row = tid >> 2;
        int seg = (tid & 3) * 32;
        int grow = brow + row; if (grow > N_NODES - 1) grow = N_NODES - 1;
        const float4* p = reinterpret_cast<const float4*>(&x[(size_t)grow * IN_DIM + seg]);
#pragma unroll
        for (int i = 0; i < 8; ++i) {
            float4 v = p[i];
            half4 hv = {(_Float16)v.x, (_Float16)v.y, (_Float16)v.z, (_Float16)v.w};
            *reinterpret_cast<half4*>(&xs[row * LDK + seg + i * 4]) = hv;
        }
    }

    const int lane = tid & 63;
    const int m0   = (tid >> 6) * 16;
    const int arow = m0 + (lane & 15);
    const int kgrp = (lane >> 4) * 8;
    const int bcol = lane & 15;
    f32x4 acc[8] = {};

#pragma unroll
    for (int half = 0; half < 2; ++half) {
        const int k0 = half * 64;
        if (half) __syncthreads();     // drain ws reads before restage
        {   // stage ws half: 128 cols x 64 k, 2 threads/col, 32 fp16 each
            int row = tid >> 1;
            int segl = (tid & 1) * 32;
            const half8* p = reinterpret_cast<const half8*>(&wt[row * 128 + k0 + segl]);
#pragma unroll
            for (int i = 0; i < 4; ++i)
                *reinterpret_cast<half8*>(&ws[row * LDKB + segl + i * 8]) = p[i];
        }
        __syncthreads();               // (also covers xs on half 0)
#pragma unroll
        for (int kk = 0; kk < 64; kk += 32) {
            half8 a = *reinterpret_cast<const half8*>(&xs[arow * LDK + k0 + kk + kgrp]);
#pragma unroll
            for (int nb = 0; nb < 8; ++nb) {
                half8 b = *reinterpret_cast<const half8*>(
                    &ws[(nb * 16 + bcol) * LDKB + kk + kgrp]);
                acc[nb] = __builtin_amdgcn_mfma_f32_16x16x32_f16(a, b, acc[nb], 0, 0, 0);
            }
        }
    }
#pragma unroll
    for (int nb = 0; nb < 8; ++nb) {
#pragma unroll
        for (int r = 0; r < 4; ++r) {
            int node = brow + m0 + (lane >> 4) * 4 + r;
            int feat = nb * 16 + bcol;
            if (node < N_NODES) h[(size_t)node * HID_DIM + feat] = (_Float16)acc[nb][r];
        }
    }
}

// ------------- k1: blocks [0,NBIN) = binA ; [NBIN,NBIN+G1) = gemm ----------
// bucket entry packed u32: (src << 9) | (dst & 511); bucket id in u8 side arr.
__global__ __launch_bounds__(256) void k_fat1(const int* __restrict__ ei,
                                              const float* __restrict__ x,
                                              const _Float16* __restrict__ wt,
                                              _Float16* __restrict__ h,
                                              int* __restrict__ gcur,
                                              unsigned* __restrict__ bucket) {
    __shared__ __align__(16) char smem[SMEM_BYTES];
    const int tid = threadIdx.x;

    if (blockIdx.x >= NBIN) {
        gemm_role(smem, tid, (blockIdx.x - NBIN) * 64, x, wt, h);
        return;
    }
    // ---------------- binA role: edges -> dst-window buckets --------------
    unsigned* stage = (unsigned*)smem;                    // 16384 B
    unsigned char* bkid = (unsigned char*)(smem + 16384); // 4096 B
    int* hist  = (int*)(smem + 20480);                    // 784 B
    int* lbase = (int*)(smem + 21264);                    // 784 B
    int* lcur  = (int*)(smem + 22048);                    // 784 B
    int* s64   = (int*)(smem + 22832);                    // 16 B
    for (int b = tid; b < NBK; b += 256) { hist[b] = 0; lcur[b] = 0; }
    if (tid < 64) {                            // int64 layout probe
        int v = ei[2 * tid + 1];
        int all0 = __all(v == 0);
        if (tid == 0) *s64 = all0;
    }
    __syncthreads();
    const int is64 = *s64;
    const int e0 = blockIdx.x * BK_EDGES;
    const int valid = min(BK_EDGES, N_EDGES - e0);

#pragma unroll
    for (int k = 0; k < 8; ++k) {
        int el = k * 512 + 2 * tid;
        if (el >= valid) break;
        int e = e0 + el;
        int s0, s1, d0, d1;
        if (is64) {
            int4 vs = reinterpret_cast<const int4*>(ei)[e >> 1];
            int4 vd = (reinterpret_cast<const int4*>(ei) + N_EDGES / 2)[e >> 1];
            s0 = vs.x; s1 = vs.z; d0 = vd.x; d1 = vd.z;
        } else {
            int2 vs = reinterpret_cast<const int2*>(ei)[e >> 1];
            int2 vd = reinterpret_cast<const int2*>(ei + N_EDGES)[e >> 1];
            s0 = vs.x; s1 = vs.y; d0 = vd.x; d1 = vd.y;
        }
        stage[el]     = ((unsigned)s0 << 9) | ((unsigned)d0 & 511u);
        stage[el + 1] = ((unsigned)s1 << 9) | ((unsigned)d1 & 511u);
        bkid[el]      = (unsigned char)(d0 >> 9);
        bkid[el + 1]  = (unsigned char)(d1 >> 9);
        atomicAdd(&hist[d0 >> 9], 1);
        atomicAdd(&hist[d1 >> 9], 1);
    }
    __syncthreads();
    for (int b = tid; b < NBK; b += 256)
        if (hist[b] > 0) lbase[b] = atomicAdd(&gcur[b], hist[b]);
    __syncthreads();
    for (int i = tid; i < valid; i += 256) {
        unsigned v = stage[i];
        int b = bkid[i];
        int pos = lbase[b] + atomicAdd(&lcur[b], 1);
        if (pos < BCAP) bucket[(size_t)b * BCAP + pos] = v;
    }
}

// ------------- k2: blocks [0,NBK) = buildB ; [NBK,NBK+G2) = gemm -----------
__global__ __launch_bounds__(256) void k_fat2(const int* __restrict__ gcur,
                                              const unsigned* __restrict__ bucket,
                                              float* __restrict__ dinv,
                                              int2* __restrict__ rc,
                                              int* __restrict__ csr_src,
                                              const float* __restrict__ x,
                                              const _Float16* __restrict__ wt,
                                              _Float16* __restrict__ h) {
    __shared__ __align__(16) char smem[SMEM_BYTES];
    const int tid = threadIdx.x;

    if (blockIdx.x >= NBK) {
        gemm_role(smem, tid, (G1 + blockIdx.x - NBK) * 64, x, wt, h);
        return;
    }
    // ---------------- buildB role (single-pass, entries in registers) -----
    int* sizes = (int*)smem;                   // 784 B
    int* ncnt  = (int*)(smem + 784);           // 2048
    int* nloff = (int*)(smem + 2832);          // 2048
    int* ncur  = (int*)(smem + 4880);          // 2048
    int* wtot  = (int*)(smem + 6928);          // 16
    int* base_p = (int*)(smem + 6944);
    const int b = blockIdx.x;
    for (int i = tid; i < NBK; i += 256) sizes[i] = gcur[i];
    ncnt[tid] = 0; ncnt[tid + 256] = 0; ncur[tid] = 0; ncur[tid + 256] = 0;
    __syncthreads();
    const int sz = min(sizes[b], BCAP);
    if (tid < 64) {                 // wave-parallel: base = sum sizes[0..b)
        int part = 0;
        for (int i = tid; i < b; i += 64) part += sizes[i];
#pragma unroll
        for (int d = 32; d; d >>= 1) part += __shfl_xor(part, d);
        if (tid == 0) *base_p = part;
    }
    const int n0 = b * 512;
    const unsigned* bk = bucket + (size_t)b * BCAP;
    unsigned ent[40];               // BCAP/256 = 40, fully unrolled (static idx)
#pragma unroll
    for (int j = 0; j < 40; ++j) {
        int i = j * 256 + tid;
        unsigned v = 0xFFFFFFFFu;
        if (i < sz) { v = bk[i]; atomicAdd(&ncnt[v & 511u], 1); }
        ent[j] = v;
    }
    __syncthreads();
    // 2-level exclusive scan over ncnt[512]
    int c0 = ncnt[2 * tid], c1 = ncnt[2 * tid + 1];
    int pair = c0 + c1;
    int lane = tid & 63, wv = tid >> 6;
    int scan = pair;
#pragma unroll
    for (int d = 1; d < 64; d <<= 1) {
        int t = __shfl_up(scan, d);
        if (lane >= d) scan += t;
    }
    if (lane == 63) wtot[wv] = scan;
    int excl = scan - pair;
    __syncthreads();
#pragma unroll
    for (int i = 0; i < 4; ++i) if (i < wv) excl += wtot[i];
    nloff[2 * tid] = excl;
    nloff[2 * tid + 1] = excl + c0;
    __syncthreads();
    const int base = *base_p;
    for (int i = tid; i < 512; i += 256) {
        int node = n0 + i;
        if (node < N_NODES) {
            int c = ncnt[i];
            dinv[node] = rsqrtf((float)(c + 1));
            rc[node] = make_int2(base + nloff[i], c);
        }
    }
#pragma unroll
    for (int j = 0; j < 40; ++j) {
        unsigned v = ent[j];
        if (v != 0xFFFFFFFFu) {
            int li = v & 511u;
            int pos = atomicAdd(&ncur[li], 1);
            csr_src[base + nloff[li] + pos] = (int)(v >> 9);
        }
    }
}

// ------- gather (round-8 proven): 16 lanes/node, chunk-32, early-exit ------
#define GSTEP(J, SE, DS) {                                                   \
    int s_ = __shfl(SE, hi | (J));                                           \
    float w_ = __shfl(DS, hi | (J));                                         \
    half8 v_ = *reinterpret_cast<const half8*>(hbase + (size_t)s_ * HID_DIM);\
    acc[0] = fmaf((float)v_[0], w_, acc[0]);                                 \
    acc[1] = fmaf((float)v_[1], w_, acc[1]);                                 \
    acc[2] = fmaf((float)v_[2], w_, acc[2]);                                 \
    acc[3] = fmaf((float)v_[3], w_, acc[3]);                                 \
    acc[4] = fmaf((float)v_[4], w_, acc[4]);                                 \
    acc[5] = fmaf((float)v_[5], w_, acc[5]);                                 \
    acc[6] = fmaf((float)v_[6], w_, acc[6]);                                 \
    acc[7] = fmaf((float)v_[7], w_, acc[7]); }
#define GGRP(B, SE, DS) \
    GSTEP(B + 0, SE, DS) GSTEP(B + 1, SE, DS) GSTEP(B + 2, SE, DS) \
    GSTEP(B + 3, SE, DS) GSTEP(B + 4, SE, DS) GSTEP(B + 5, SE, DS) \
    GSTEP(B + 6, SE, DS) GSTEP(B + 7, SE, DS)

__global__ __launch_bounds__(256) void k_gather(const _Float16* __restrict__ h,
                                                const int* __restrict__ csr_src,
                                                const int2* __restrict__ rc,
                                                const float* __restrict__ dinv,
                                                const float* __restrict__ bias,
                                                float* __restrict__ out) {
    const int lane = threadIdx.x & 63;
    const int l4   = lane & 15;
    const int hi   = lane & 48;
    const int node = blockIdx.x * 16 + (threadIdx.x >> 6) * 4 + (lane >> 4);
    const int2 rcv = rc[node];
    const int rs = rcv.x;
    const int n  = rcv.y;
    const float di = dinv[node];
    const int tq = n + 1;                 // slots incl self loop
    const _Float16* hbase = h + l4 * 8;

    float acc[8] = {};

    for (int c0 = 0; c0 < tq; c0 += 32) {
        int t0 = c0 + l4, t1 = t0 + 16;
        int se0 = node, se1 = node;
        float dw0 = 0.0f, dw1 = 0.0f;
        if (t0 < n)       { se0 = csr_src[rs + t0]; dw0 = dinv[se0]; }
        else if (t0 == n)   dw0 = di;
        if (t1 < n)       { se1 = csr_src[rs + t1]; dw1 = dinv[se1]; }
        else if (t1 == n)   dw1 = di;

        GGRP(0, se0, dw0)
        if (tq <= c0 + 8) continue;
        GGRP(8, se0, dw0)
        if (tq <= c0 + 16) continue;
        GGRP(0, se1, dw1)
        if (tq <= c0 + 24) continue;
        GGRP(8, se1, dw1)
    }

    float4 bv0 = *reinterpret_cast<const float4*>(&bias[l4 * 8]);
    float4 bv1 = *reinterpret_cast<const float4*>(&bias[l4 * 8 + 4]);
    float4 o0, o1;
    o0.x = fmaxf(fmaf(di, acc[0], bv0.x), 0.0f);
    o0.y = fmaxf(fmaf(di, acc[1], bv0.y), 0.0f);
    o0.z = fmaxf(fmaf(di, acc[2], bv0.z), 0.0f);
    o0.w = fmaxf(fmaf(di, acc[3], bv0.w), 0.0f);
    o1.x = fmaxf(fmaf(di, acc[4], bv1.x), 0.0f);
    o1.y = fmaxf(fmaf(di, acc[5], bv1.y), 0.0f);
    o1.z = fmaxf(fmaf(di, acc[6], bv1.z), 0.0f);
    o1.w = fmaxf(fmaf(di, acc[7], bv1.w), 0.0f);
    float* op = &out[(size_t)node * HID_DIM + l4 * 8];
    *reinterpret_cast<float4*>(op)     = o0;
    *reinterpret_cast<float4*>(op + 4) = o1;
}

// ---------------- launcher --------------------------------------------------
extern "C" void kernel_launch(void* const* d_in, const int* in_sizes, int n_in,
                              void* d_out, int out_size, void* d_ws, size_t ws_size,
                              hipStream_t stream) {
    const float* x    = (const float*)d_in[0];
    const int*   ei   = (const int*)d_in[1];
    const float* w    = (const float*)d_in[2];
    const float* bias = (const float*)d_in[3];
    float* out = (float*)d_out;

    // workspace layout (bytes), 16B-aligned; ~41.3 MB total
    char* wsb = (char*)d_ws;
    _Float16* h      = (_Float16*)(wsb);                  // 25,600,000
    float* dinv      = (float*)(wsb + 25600000);          // 400,000
    int2*  rc        = (int2*)(wsb + 26000000);           // 800,000
    int*   csr_src   = (int*)(wsb + 26800000);            // 6,400,000
    unsigned* bucket = (unsigned*)(wsb + 33200000);       // 196*10240*4 = 8,028,160
    _Float16* wt     = (_Float16*)(wsb + 41228160);       // 32,768
    int*   gcur      = (int*)(wsb + 41260928);            // 800

    k_prep  <<<64, 256, 0, stream>>>(gcur, w, wt);
    k_fat1  <<<NBIN + G1, 256, 0, stream>>>(ei, x, wt, h, gcur, bucket);
    k_fat2  <<<NBK + G2, 256, 0, stream>>>(gcur, bucket, dinv, rc, csr_src, x, wt, h);
    k_gather<<<N_NODES / 16, 256, 0, stream>>>(h, csr_src, rc, dinv, bias, out);
}